// Round 15
// baseline (935.693 us; speedup 1.0000x reference)
//
#include <hip/hip_runtime.h>
#include <hip/hip_bf16.h>
#include <math.h>

// B=32 graphs, N=256 nodes/graph, D=128.
#define DD   128
#define NPG  256
#define NGR  32
#define TTOT 8192
#define LOG2E  1.4426950408889634f
#define LOG2E2 2.8853900817779268f   // 2*log2(e)
#define KSTRIDE 264                   // LDS floats per transposed key row
#define SSTR    268                   // spartS row stride
#define H2A(j)  ((j) + (((j)>>5)<<3))   // stagger: chunk base -> bank chunk*8
#define PAD16(j) ((j) + (((j)>>4)<<2))  // q/v pad: d -> d + (d>>4)*4

__device__ __forceinline__ float dot4(float4 a, float4 b){
  return a.x*b.x + a.y*b.y + a.z*b.z + a.w*b.w;
}
// ---- DPP cross-lane (VALU pipe; keeps ds_bpermute off critical chains) ----
// Semantics (verified via dpp_wave_sum's lane-63 accumulation):
//   row_shr:N (0x110|N): lane i RECEIVES from lane i-N (toward higher lanes)
//   row_shl:N (0x100|N): lane i RECEIVES from lane i+N (toward lower lanes)
template<int CTRL, int RMASK>
__device__ __forceinline__ float upd_f(float oldv, float x){
  return __int_as_float(__builtin_amdgcn_update_dpp(
      __float_as_int(oldv), __float_as_int(x), CTRL, RMASK, 0xf, false));
}
__device__ __forceinline__ float dpp_xor1(float x){
  return __int_as_float(__builtin_amdgcn_mov_dpp(__float_as_int(x), 0xB1, 0xf, 0xf, false));
}
__device__ __forceinline__ float dpp_xor2(float x){
  return __int_as_float(__builtin_amdgcn_mov_dpp(__float_as_int(x), 0x4E, 0xf, 0xf, false));
}
// 8-lane group sums. After xor1+xor2: lanes {8g..8g+3}=Qlo, {8g+4..8g+7}=Qhi.
// red8_lo: row_shl:4 -> lane 8g   receives lane 8g+4 (Qhi)  => full sum at u==0.
// red8_hi: row_shr:4 -> lane 8g+4 receives lane 8g   (Qlo)  => full sum at u==4.
// (R14 BUG: these two ctrl codes were swapped -> half-sums + cross-group reads.)
__device__ __forceinline__ float red8_lo(float x){
  x += dpp_xor1(x); x += dpp_xor2(x);
  x += upd_f<0x104,0xf>(0.f, x);   // row_shl:4
  return x;
}
__device__ __forceinline__ float red8_hi(float x){
  x += dpp_xor1(x); x += dpp_xor2(x);
  x += upd_f<0x114,0xf>(0.f, x);   // row_shr:4
  return x;
}
__device__ __forceinline__ float dpp_wave_sum(float x){
  x += upd_f<0x111,0xf>(0.f, x);   // row_shr:1
  x += upd_f<0x112,0xf>(0.f, x);   // row_shr:2
  x += upd_f<0x114,0xf>(0.f, x);   // row_shr:4
  x += upd_f<0x118,0xf>(0.f, x);   // row_shr:8
  x += upd_f<0x142,0xa>(0.f, x);   // row_bcast15
  x += upd_f<0x143,0xc>(0.f, x);   // row_bcast31
  return __uint_as_float(__builtin_amdgcn_readlane(__float_as_uint(x), 63));
}
__device__ __forceinline__ float dpp_wave_max(float x){
  const float NI = -INFINITY;
  x = fmaxf(x, upd_f<0x111,0xf>(NI, x));
  x = fmaxf(x, upd_f<0x112,0xf>(NI, x));
  x = fmaxf(x, upd_f<0x114,0xf>(NI, x));
  x = fmaxf(x, upd_f<0x118,0xf>(NI, x));
  x = fmaxf(x, upd_f<0x142,0xa>(NI, x));
  x = fmaxf(x, upd_f<0x143,0xc>(NI, x));
  return __uint_as_float(__builtin_amdgcn_readlane(__float_as_uint(x), 63));
}
__device__ __forceinline__ float sigfast(float x){
  return __builtin_amdgcn_rcpf(1.f + __builtin_amdgcn_exp2f(-x*LOG2E));
}
__device__ __forceinline__ float tanhfast(float y){
  return 1.f - 2.f*__builtin_amdgcn_rcpf(1.f + __builtin_amdgcn_exp2f(y*LOG2E2));
}

// ---------------- Kernel 1: parallel precompute (R9/R12 SCALAR version) ----------------
// SCALAR mm_tile accumulation order is part of the validated-numerics contract
// (R10's float4 reorder flipped a near-tie argmax -> tour divergence). DO NOT vectorize.
// keysE[d][n] = exp(2 * l2norm(relu(emb@Wk1.T+bk1)@Wk2.T+bk2)[n][d])  [128][8192] TRANSPOSED
// gi_all = emb@W_ih.T + b_ih                                          [8192,384]

__device__ __forceinline__ void load_w128(float* Ws, const float* __restrict__ W, int t){
  const float4* src = (const float4*)W;
  #pragma unroll
  for (int m=0;m<16;m++){
    int idx = m*256+t; int r = idx>>5, c4 = idx&31;
    float4 val = src[idx];
    float* dst = &Ws[r*129 + c4*4];
    dst[0]=val.x; dst[1]=val.y; dst[2]=val.z; dst[3]=val.w;
  }
}

__device__ __forceinline__ void mm_tile(const float* __restrict__ inS, const float* __restrict__ Ws,
                                        float acc[4][4], int jg, int ng){
  #pragma unroll
  for(int r=0;r<4;r++)
    #pragma unroll
    for(int c=0;c<4;c++) acc[r][c]=0.f;
  #pragma unroll 4
  for (int k=0;k<128;k++){
    float w[4], x[4];
    #pragma unroll
    for (int r=0;r<4;r++) w[r] = Ws[(jg*4+r)*129+k];
    #pragma unroll
    for (int c=0;c<4;c++) x[c] = inS[(ng*4+c)*129+k];
    #pragma unroll
    for (int r=0;r<4;r++)
      #pragma unroll
      for (int c=0;c<4;c++) acc[r][c] += w[r]*x[c];
  }
}

__global__ __launch_bounds__(256) void precompute_kernel(
    const float* __restrict__ emb,
    const float* __restrict__ Wk1, const float* __restrict__ bk1,
    const float* __restrict__ Wk2, const float* __restrict__ bk2,
    const float* __restrict__ Wih, const float* __restrict__ bih,
    float* __restrict__ keysE, float* __restrict__ giall)
{
  __shared__ __align__(16) float xs[32*129];
  __shared__ __align__(16) float Ws[128*129];
  __shared__ __align__(16) float hs[32*129];
  __shared__ __align__(16) float os[32*129];
  __shared__ float nrm[32];
  const int t  = threadIdx.x;
  const int n0 = blockIdx.x * 32;
  const int ng = t & 7, jg = t >> 3;

  {
    const float4* src = (const float4*)emb + (size_t)n0*32;
    #pragma unroll
    for (int m=0;m<4;m++){
      int idx = m*256+t; int n = idx>>5, c4 = idx&31;
      float4 val = src[idx];
      float* dst = &xs[n*129 + c4*4];
      dst[0]=val.x; dst[1]=val.y; dst[2]=val.z; dst[3]=val.w;
    }
  }
  load_w128(Ws, Wk1, t);
  __syncthreads();
  {
    float acc[4][4];
    mm_tile(xs, Ws, acc, jg, ng);
    #pragma unroll
    for (int r=0;r<4;r++){
      float bb = bk1[jg*4+r];
      #pragma unroll
      for (int c=0;c<4;c++) hs[(ng*4+c)*129 + jg*4+r] = fmaxf(acc[r][c]+bb, 0.f);
    }
  }
  __syncthreads();
  load_w128(Ws, Wk2, t);
  __syncthreads();
  {
    float acc[4][4];
    mm_tile(hs, Ws, acc, jg, ng);
    #pragma unroll
    for (int r=0;r<4;r++){
      float bb = bk2[jg*4+r];
      #pragma unroll
      for (int c=0;c<4;c++) os[(ng*4+c)*129 + jg*4+r] = acc[r][c]+bb;
    }
  }
  __syncthreads();
  if (t<32){
    float ss=0.f;
    for (int j=0;j<128;j++){ float x = os[t*129+j]; ss += x*x; }
    nrm[t] = fmaxf(sqrtf(ss), 1e-12f);
  }
  __syncthreads();
  // transposed E-keys: keysE[d][n] = exp(2*K)
  #pragma unroll
  for (int m=0;m<16;m++){
    int idx = m*256+t; int nl = idx & 31, d = idx >> 5;
    float kk = os[nl*129 + d] / nrm[nl];
    keysE[(size_t)d*TTOT + n0 + nl] = __builtin_amdgcn_exp2f(kk * LOG2E2);
  }
  for (int c=0;c<3;c++){
    __syncthreads();
    load_w128(Ws, Wih + c*16384, t);
    __syncthreads();
    float acc[4][4];
    mm_tile(xs, Ws, acc, jg, ng);
    #pragma unroll
    for (int r=0;r<4;r++){
      float bb = bih[c*128 + jg*4+r];
      #pragma unroll
      for (int cc=0;cc<4;cc++)
        giall[(size_t)(n0 + ng*4+cc)*384 + c*128 + jg*4 + r] = acc[r][cc] + bb;
    }
  }
}

// ---------------- Kernel 2: sequential decode ----------------
// 32 blocks x 512 threads; 255 steps; 4 barriers/step.
// Matvec: 8-lane groups x 16-float k-chunks, pair of output rows per group ->
// 4 ds_read_b128/lane/phase (halves the dominant LDS-pipe load). Reduction
// via red8_lo/red8_hi (direction-corrected vs R14). 160 persistent floats.
// Combine + score read guards skip cols >= V (exact).

__global__ __launch_bounds__(512, 2) void decode_kernel(
    const float* __restrict__ emb,
    const float* __restrict__ keysE, const float* __restrict__ giall,
    const float* __restrict__ Whh, const float* __restrict__ bhh,
    const float* __restrict__ Wq1, const float* __restrict__ bq1,
    const float* __restrict__ Wq2, const float* __restrict__ bq2,
    const float* __restrict__ v,   const float* __restrict__ Wh,
    const float* __restrict__ bh,  const int* __restrict__ start_nodes,
    float* __restrict__ tours_o, float* __restrict__ lp_o)
{
  __shared__ __align__(16) float keys_s[128*KSTRIDE];  // 132 KB, transposed E-keys
  __shared__ __align__(16) float h_s[2][160];          // staggered (H2A)
  __shared__ __align__(16) float qh_s[160];            // staggered (H2A)
  __shared__ __align__(16) float q_s[160];             // PAD16 (raw q), also gctx scratch
  __shared__ __align__(16) float v_sp[160];            // PAD16 layout, -2*v
  __shared__ __align__(16) float spartS[8*SSTR];       // score partials (+init scratch)
  __shared__ int col2node_s[256], node2col_s[256];
  __shared__ float red2[8];

  const int t = threadIdx.x;
  const int b = blockIdx.x;
  const int w  = t >> 6, L  = t & 63;
  const int G  = t >> 3, u = t & 7;     // 64 groups x 8 lanes (matvec)
  const int sel = (t >> 2) & 1;         // which row of the group's pair
  const int myrow = 2*G + sel;          // output row for active lanes
  const int act = ((t & 3) == 0);       // active-lane predicate (u==0 or u==4)
  const int oct = L & 7, dgrp = L >> 3; // score: col-octet, dim-group

  // register weights (160 persistent floats):
  // whh6[r][i]: r=0..2 rows {2G,128+2G,256+2G}; r=3..5 rows {2G+1,...}; chunk u*16
  float4 whh6[6][4], wq14[8], wq24[8];
  {
    const float4* p0 = (const float4*)(Whh + (size_t)(2*G      )*128 + u*16);
    const float4* p1 = (const float4*)(Whh + (size_t)(128+2*G  )*128 + u*16);
    const float4* p2 = (const float4*)(Whh + (size_t)(256+2*G  )*128 + u*16);
    const float4* p3 = (const float4*)(Whh + (size_t)(2*G+1    )*128 + u*16);
    const float4* p4 = (const float4*)(Whh + (size_t)(128+2*G+1)*128 + u*16);
    const float4* p5 = (const float4*)(Whh + (size_t)(256+2*G+1)*128 + u*16);
    const float4* q1a = (const float4*)(Wq1 + (size_t)(2*G  )*128 + u*16);
    const float4* q1b = (const float4*)(Wq1 + (size_t)(2*G+1)*128 + u*16);
    const float4* q2a = (const float4*)(Wq2 + (size_t)(2*G  )*128 + u*16);
    const float4* q2b = (const float4*)(Wq2 + (size_t)(2*G+1)*128 + u*16);
    #pragma unroll
    for (int i=0;i<4;i++){
      whh6[0][i]=p0[i]; whh6[1][i]=p1[i]; whh6[2][i]=p2[i];
      whh6[3][i]=p3[i]; whh6[4][i]=p4[i]; whh6[5][i]=p5[i];
      wq14[i]=q1a[i]; wq14[4+i]=q1b[i];
      wq24[i]=q2a[i]; wq24[4+i]=q2b[i];
    }
  }
  const float br = bhh[myrow], bz = bhh[128+myrow], bn = bhh[256+myrow];
  const float b1g = bq1[myrow], b2g = bq2[myrow];
  // h-chunk base in H2A layout: floats [u*16, u*16+16) -> contiguous, aligned
  const int hoff = u*16 + (u>>1)*8;

  if (t<128) v_sp[PAD16(t)] = -2.f * v[t];
  if (t<256){ col2node_s[t] = t; node2col_s[t] = t; }
  { // stage transposed E-keys: coalesced per d-row
    #pragma unroll
    for (int m=0;m<16;m++){
      int idx = m*512 + t; int d = idx>>6, q = idx&63;
      *(float4*)(keys_s + d*KSTRIDE + q*4) =
        *(const float4*)(keysE + (size_t)d*TTOT + b*256 + q*4);
    }
  }
  { // graph-context partial sums (4 parts x 64 nodes)
    int d = t & 127, part = t >> 7;
    float a = 0.f;
    const float* base = emb + (size_t)(b*256 + part*64)*128 + d;
    for (int i=0;i<64;i++) a += base[(size_t)i*128];
    spartS[part*128+d] = a;
  }
  int cur = start_nodes[b];
  __syncthreads();
  if (t<128){
    float a = 0.f;
    #pragma unroll
    for (int p=0;p<4;p++) a += spartS[p*128+t];
    q_s[t] = a * (1.f/256.f);          // gctx temp (plain idx, init only)
  }
  __syncthreads();
  if (t<128){ // hidden0 = gctx@Wh.T + bh  (write staggered)
    float a = bh[t];
    const float* wr = Wh + (size_t)t*128;
    for (int k=0;k<128;k++) a += wr[k]*q_s[k];
    h_s[0][H2A(t)] = a;
  }
  { // sv = sum(v)
    float xv = (t<128) ? v[t] : 0.f;
    float tot = dpp_wave_sum(xv);
    if (L==0) red2[w] = tot;
  }
  __syncthreads();
  float sv = 0.f;
  #pragma unroll
  for (int i=0;i<8;i++) sv += red2[i];

  // gi prefetch for step 0
  float gir=0.f, giz=0.f, gin=0.f;
  if (act){
    const float* gp = giall + (size_t)cur*384 + myrow;
    gir = gp[0]; giz = gp[128]; gin = gp[256];
  }

  for (int step=0; step<255; step++){
    const int par = step & 1;
    const int V   = 255 - step;          // valid count after removing cur
    const int curl = cur - b*256;

    // ---- swap-remove cur's keys column (waves 2-3; reads PRE-update map) ----
    if (t >= 128 && t < 256){
      int r = t - 128;
      int px = node2col_s[curl];
      keys_s[r*KSTRIDE + px] = keys_s[r*KSTRIDE + V];
    }
    if (t == 384) tours_o[b*256+step] = (float)cur;   // wave 6

    // ---- phase A: gh dots (pair of rows per group) + fused GRU ----
    {
      const float4* hc4 = (const float4*)(h_s[par] + hoff);
      float4 hv0 = hc4[0], hv1 = hc4[1], hv2 = hc4[2], hv3 = hc4[3];
      float a0 = dot4(whh6[0][0],hv0)+dot4(whh6[0][1],hv1)+dot4(whh6[0][2],hv2)+dot4(whh6[0][3],hv3);
      float a1 = dot4(whh6[1][0],hv0)+dot4(whh6[1][1],hv1)+dot4(whh6[1][2],hv2)+dot4(whh6[1][3],hv3);
      float a2 = dot4(whh6[2][0],hv0)+dot4(whh6[2][1],hv1)+dot4(whh6[2][2],hv2)+dot4(whh6[2][3],hv3);
      float a3 = dot4(whh6[3][0],hv0)+dot4(whh6[3][1],hv1)+dot4(whh6[3][2],hv2)+dot4(whh6[3][3],hv3);
      float a4 = dot4(whh6[4][0],hv0)+dot4(whh6[4][1],hv1)+dot4(whh6[4][2],hv2)+dot4(whh6[4][3],hv3);
      float a5 = dot4(whh6[5][0],hv0)+dot4(whh6[5][1],hv1)+dot4(whh6[5][2],hv2)+dot4(whh6[5][3],hv3);
      a0 = red8_lo(a0); a1 = red8_lo(a1); a2 = red8_lo(a2);   // valid at u==0
      a3 = red8_hi(a3); a4 = red8_hi(a4); a5 = red8_hi(a5);   // valid at u==4
      if (act){
        float gr = sel ? a3 : a0;
        float gz = sel ? a4 : a1;
        float gn = sel ? a5 : a2;
        float r = sigfast(gir + gr + br);
        float z = sigfast(giz + gz + bz);
        float n = tanhfast(gin + r*(gn + bn));
        h_s[par^1][H2A(myrow)] = (1.f-z)*n + z*h_s[par][H2A(myrow)];
      }
    }
    __syncthreads();                                   // B1

    // ---- deferred index-map update (wave 7; race-free: all prev-step
    //      combine reads of col2node_s completed before B1) ----
    if (t == 448){
      int px = node2col_s[curl];
      int ln = col2node_s[V];
      col2node_s[px] = ln;
      node2col_s[ln] = px;
    }

    { // qh = relu(h@Wq1.T + bq1), pair of rows per group
      const float4* hc4 = (const float4*)(h_s[par^1] + hoff);
      float4 hv0 = hc4[0], hv1 = hc4[1], hv2 = hc4[2], hv3 = hc4[3];
      float a0 = dot4(wq14[0],hv0)+dot4(wq14[1],hv1)+dot4(wq14[2],hv2)+dot4(wq14[3],hv3);
      float a1 = dot4(wq14[4],hv0)+dot4(wq14[5],hv1)+dot4(wq14[6],hv2)+dot4(wq14[7],hv3);
      a0 = red8_lo(a0); a1 = red8_hi(a1);
      if (act) qh_s[H2A(myrow)] = fmaxf((sel ? a1 : a0) + b1g, 0.f);
    }
    __syncthreads();                                   // B2

    { // q_raw = qh@Wq2.T + bq2 (PAD16 store) ; per-wave ssq via DPP
      const float4* qc4 = (const float4*)(qh_s + hoff);
      float4 qv0 = qc4[0], qv1 = qc4[1], qv2 = qc4[2], qv3 = qc4[3];
      float a0 = dot4(wq24[0],qv0)+dot4(wq24[1],qv1)+dot4(wq24[2],qv2)+dot4(wq24[3],qv3);
      float a1 = dot4(wq24[4],qv0)+dot4(wq24[5],qv1)+dot4(wq24[6],qv2)+dot4(wq24[7],qv3);
      a0 = red8_lo(a0); a1 = red8_hi(a1);
      float qval = (sel ? a1 : a0) + b2g;
      if (act) q_s[PAD16(myrow)] = qval;
      float ssp = act ? qval*qval : 0.f;
      float tot = dpp_wave_sum(ssp);
      if (L==0) red2[w] = tot;
    }
    __syncthreads();                                   // B3

    // ---- score: wave w -> cols 32w..32w+31 (wave skip when 32w >= V;
    //      per-lane skip when its 4-col strip starts >= V) ----
    if (32*w < V){
      float ss = 0.f;
      #pragma unroll
      for (int i=0;i<8;i++) ss += red2[i];
      float rn = 1.f / fmaxf(sqrtf(ss), 1e-12f);
      if (32*w + oct*4 < V){
        const float* kbase = keys_s + dgrp*16*KSTRIDE + 32*w + oct*4;
        const float* qb    = q_s  + dgrp*20;
        const float* vbase = v_sp + dgrp*20;
        float4 acc = {0.f,0.f,0.f,0.f};
        #pragma unroll
        for (int jj=0;jj<16;jj++){
          float eqj = __builtin_amdgcn_exp2f(qb[jj] * rn * LOG2E2);
          float vj  = vbase[jj];
          float4 K = *(const float4*)(kbase + jj*KSTRIDE);
          float r0 = __builtin_amdgcn_rcpf(fmaf(K.x, eqj, 1.f));
          float r1 = __builtin_amdgcn_rcpf(fmaf(K.y, eqj, 1.f));
          float r2 = __builtin_amdgcn_rcpf(fmaf(K.z, eqj, 1.f));
          float r3 = __builtin_amdgcn_rcpf(fmaf(K.w, eqj, 1.f));
          acc.x = fmaf(vj, r0, acc.x);
          acc.y = fmaf(vj, r1, acc.y);
          acc.z = fmaf(vj, r2, acc.z);
          acc.w = fmaf(vj, r3, acc.w);
        }
        *(float4*)(spartS + dgrp*SSTR + 32*w + oct*4) = acc;
      }
    }
    __syncthreads();                                   // Bs1

    // ---- redundant combine: EVERY wave reduces cols < V; every lane
    //      learns argmax + softmax sum -> no extra barrier ----
    {
      float sx=0.f, sy=0.f, sz=0.f, sw=0.f;
      int c0 = 4*L;
      if (c0 < V){
        const float* sp = spartS + c0;
        #pragma unroll
        for (int i=0;i<8;i++){
          float4 p = *(const float4*)(sp + i*SSTR);
          sx += p.x; sy += p.y; sz += p.z; sw += p.w;
        }
      }
      float vx = (c0+0 < V) ? sv+sx : -INFINITY;
      float vy = (c0+1 < V) ? sv+sy : -INFINITY;
      float vz = (c0+2 < V) ? sv+sz : -INFINITY;
      float vw = (c0+3 < V) ? sv+sw : -INFINITY;
      float bm = vx; int bc = c0;                 // first-max tie-break
      if (vy > bm){ bm=vy; bc=c0+1; }
      if (vz > bm){ bm=vz; bc=c0+2; }
      if (vw > bm){ bm=vw; bc=c0+3; }
      float m = dpp_wave_max(bm);
      unsigned long long mk = __ballot(bm == m);
      int flane = __ffsll(mk) - 1;                // lowest lane = lowest col
      int besti = __builtin_amdgcn_readlane(bc, flane);
      float es = __builtin_amdgcn_exp2f((vx-m)*LOG2E) + __builtin_amdgcn_exp2f((vy-m)*LOG2E)
               + __builtin_amdgcn_exp2f((vz-m)*LOG2E) + __builtin_amdgcn_exp2f((vw-m)*LOG2E);
      float S = dpp_wave_sum(es);
      cur = b*256 + col2node_s[besti];            // read pre-next-update map
      if (act){   // prefetch next gi (consumed in next phase A)
        const float* gp = giall + (size_t)cur*384 + myrow;
        gir = gp[0]; giz = gp[128]; gin = gp[256];
      }
      if (t==320) lp_o[b*255+step] = logf(1.f/S + 1e-10f);  // wave 5
    }
    // no barrier: next step's keys-swap/phase-A touch no combine-read state
  }
  if (t==0) tours_o[b*256+255] = (float)cur;
}

extern "C" void kernel_launch(void* const* d_in, const int* in_sizes, int n_in,
                              void* d_out, int out_size, void* d_ws, size_t ws_size,
                              hipStream_t stream) {
  const float* emb  = (const float*)d_in[0];
  const int*   startn = (const int*)d_in[1];
  const float* Wq1 = (const float*)d_in[3];  const float* bq1 = (const float*)d_in[4];
  const float* Wq2 = (const float*)d_in[5];  const float* bq2 = (const float*)d_in[6];
  const float* Wk1 = (const float*)d_in[7];  const float* bk1 = (const float*)d_in[8];
  const float* Wk2 = (const float*)d_in[9];  const float* bk2 = (const float*)d_in[10];
  const float* Wih = (const float*)d_in[11]; const float* Whh = (const float*)d_in[12];
  const float* bih = (const float*)d_in[13]; const float* bhh = (const float*)d_in[14];
  const float* v   = (const float*)d_in[15]; const float* Wh  = (const float*)d_in[16];
  const float* bh  = (const float*)d_in[17];

  float* keysE = (float*)d_ws;               // exp(2*keys) TRANSPOSED [128][8192]
  float* giall = keysE + (size_t)TTOT*DD;    // [8192*384]

  float* outp = (float*)d_out;   // tours [32*256] then log_probs [32*255]

  precompute_kernel<<<256, 256, 0, stream>>>(emb, Wk1, bk1, Wk2, bk2, Wih, bih, keysE, giall);
  decode_kernel<<<NGR, 512, 0, stream>>>(emb, keysE, giall, Whh, bhh, Wq1, bq1, Wq2, bq2,
                                         v, Wh, bh, startn, outp, outp + TTOT);
}

// Round 16
// 923.589 us; speedup vs baseline: 1.0131x; 1.0131x over previous
//
#include <hip/hip_runtime.h>
#include <hip/hip_bf16.h>
#include <math.h>

// B=32 graphs, N=256 nodes/graph, D=128.
#define DD   128
#define NPG  256
#define NGR  32
#define TTOT 8192
#define LOG2E  1.4426950408889634f
#define LOG2E2 2.8853900817779268f   // 2*log2(e)
#define KSTRIDE 264                   // LDS floats per transposed key row
#define SSTR    268                   // spartS row stride
#define PAD16(j) ((j) + (((j)>>4)<<2))  // 16-float chunks at stride 20:
                                        // bases mod 32 = {0,20,8,28,16,4,24,12} -> 8 distinct quads

__device__ __forceinline__ float dot4(float4 a, float4 b){
  return a.x*b.x + a.y*b.y + a.z*b.z + a.w*b.w;
}
// ---- DPP cross-lane (VALU pipe; keeps ds_bpermute off critical chains) ----
// Semantics: row_shr:N -> lane i receives from lane i-N; row_shl:N -> from i+N.
template<int CTRL, int RMASK>
__device__ __forceinline__ float upd_f(float oldv, float x){
  return __int_as_float(__builtin_amdgcn_update_dpp(
      __float_as_int(oldv), __float_as_int(x), CTRL, RMASK, 0xf, false));
}
__device__ __forceinline__ float dpp_xor1(float x){
  return __int_as_float(__builtin_amdgcn_mov_dpp(__float_as_int(x), 0xB1, 0xf, 0xf, false));
}
__device__ __forceinline__ float dpp_xor2(float x){
  return __int_as_float(__builtin_amdgcn_mov_dpp(__float_as_int(x), 0x4E, 0xf, 0xf, false));
}
// 8-lane group sums. After xor1+xor2: lanes {8g..8g+3}=Qlo, {8g+4..8g+7}=Qhi.
// red8_lo: row_shl:4 -> lane 8g   += lane 8g+4 (Qhi) => full sum at u==0.
// red8_hi: row_shr:4 -> lane 8g+4 += lane 8g   (Qlo) => full sum at u==4.
__device__ __forceinline__ float red8_lo(float x){
  x += dpp_xor1(x); x += dpp_xor2(x);
  x += upd_f<0x104,0xf>(0.f, x);   // row_shl:4
  return x;
}
__device__ __forceinline__ float red8_hi(float x){
  x += dpp_xor1(x); x += dpp_xor2(x);
  x += upd_f<0x114,0xf>(0.f, x);   // row_shr:4
  return x;
}
__device__ __forceinline__ float dpp_wave_sum(float x){
  x += upd_f<0x111,0xf>(0.f, x);   // row_shr:1
  x += upd_f<0x112,0xf>(0.f, x);   // row_shr:2
  x += upd_f<0x114,0xf>(0.f, x);   // row_shr:4
  x += upd_f<0x118,0xf>(0.f, x);   // row_shr:8
  x += upd_f<0x142,0xa>(0.f, x);   // row_bcast15
  x += upd_f<0x143,0xc>(0.f, x);   // row_bcast31
  return __uint_as_float(__builtin_amdgcn_readlane(__float_as_uint(x), 63));
}
__device__ __forceinline__ float dpp_wave_max(float x){
  const float NI = -INFINITY;
  x = fmaxf(x, upd_f<0x111,0xf>(NI, x));
  x = fmaxf(x, upd_f<0x112,0xf>(NI, x));
  x = fmaxf(x, upd_f<0x114,0xf>(NI, x));
  x = fmaxf(x, upd_f<0x118,0xf>(NI, x));
  x = fmaxf(x, upd_f<0x142,0xa>(NI, x));
  x = fmaxf(x, upd_f<0x143,0xc>(NI, x));
  return __uint_as_float(__builtin_amdgcn_readlane(__float_as_uint(x), 63));
}
__device__ __forceinline__ float sigfast(float x){
  return __builtin_amdgcn_rcpf(1.f + __builtin_amdgcn_exp2f(-x*LOG2E));
}
__device__ __forceinline__ float tanhfast(float y){
  return 1.f - 2.f*__builtin_amdgcn_rcpf(1.f + __builtin_amdgcn_exp2f(y*LOG2E2));
}

// ---------------- Kernel 1: parallel precompute (R9/R12 SCALAR version) ----------------
// SCALAR mm_tile accumulation order is part of the validated-numerics contract
// (R10's float4 reorder flipped a near-tie argmax -> tour divergence). DO NOT vectorize.
// keysE[d][n] = exp(2 * l2norm(relu(emb@Wk1.T+bk1)@Wk2.T+bk2)[n][d])  [128][8192] TRANSPOSED
// gi_all = emb@W_ih.T + b_ih                                          [8192,384]

__device__ __forceinline__ void load_w128(float* Ws, const float* __restrict__ W, int t){
  const float4* src = (const float4*)W;
  #pragma unroll
  for (int m=0;m<16;m++){
    int idx = m*256+t; int r = idx>>5, c4 = idx&31;
    float4 val = src[idx];
    float* dst = &Ws[r*129 + c4*4];
    dst[0]=val.x; dst[1]=val.y; dst[2]=val.z; dst[3]=val.w;
  }
}

__device__ __forceinline__ void mm_tile(const float* __restrict__ inS, const float* __restrict__ Ws,
                                        float acc[4][4], int jg, int ng){
  #pragma unroll
  for(int r=0;r<4;r++)
    #pragma unroll
    for(int c=0;c<4;c++) acc[r][c]=0.f;
  #pragma unroll 4
  for (int k=0;k<128;k++){
    float w[4], x[4];
    #pragma unroll
    for (int r=0;r<4;r++) w[r] = Ws[(jg*4+r)*129+k];
    #pragma unroll
    for (int c=0;c<4;c++) x[c] = inS[(ng*4+c)*129+k];
    #pragma unroll
    for (int r=0;r<4;r++)
      #pragma unroll
      for (int c=0;c<4;c++) acc[r][c] += w[r]*x[c];
  }
}

__global__ __launch_bounds__(256) void precompute_kernel(
    const float* __restrict__ emb,
    const float* __restrict__ Wk1, const float* __restrict__ bk1,
    const float* __restrict__ Wk2, const float* __restrict__ bk2,
    const float* __restrict__ Wih, const float* __restrict__ bih,
    float* __restrict__ keysE, float* __restrict__ giall)
{
  __shared__ __align__(16) float xs[32*129];
  __shared__ __align__(16) float Ws[128*129];
  __shared__ __align__(16) float hs[32*129];
  __shared__ __align__(16) float os[32*129];
  __shared__ float nrm[32];
  const int t  = threadIdx.x;
  const int n0 = blockIdx.x * 32;
  const int ng = t & 7, jg = t >> 3;

  {
    const float4* src = (const float4*)emb + (size_t)n0*32;
    #pragma unroll
    for (int m=0;m<4;m++){
      int idx = m*256+t; int n = idx>>5, c4 = idx&31;
      float4 val = src[idx];
      float* dst = &xs[n*129 + c4*4];
      dst[0]=val.x; dst[1]=val.y; dst[2]=val.z; dst[3]=val.w;
    }
  }
  load_w128(Ws, Wk1, t);
  __syncthreads();
  {
    float acc[4][4];
    mm_tile(xs, Ws, acc, jg, ng);
    #pragma unroll
    for (int r=0;r<4;r++){
      float bb = bk1[jg*4+r];
      #pragma unroll
      for (int c=0;c<4;c++) hs[(ng*4+c)*129 + jg*4+r] = fmaxf(acc[r][c]+bb, 0.f);
    }
  }
  __syncthreads();
  load_w128(Ws, Wk2, t);
  __syncthreads();
  {
    float acc[4][4];
    mm_tile(hs, Ws, acc, jg, ng);
    #pragma unroll
    for (int r=0;r<4;r++){
      float bb = bk2[jg*4+r];
      #pragma unroll
      for (int c=0;c<4;c++) os[(ng*4+c)*129 + jg*4+r] = acc[r][c]+bb;
    }
  }
  __syncthreads();
  if (t<32){
    float ss=0.f;
    for (int j=0;j<128;j++){ float x = os[t*129+j]; ss += x*x; }
    nrm[t] = fmaxf(sqrtf(ss), 1e-12f);
  }
  __syncthreads();
  // transposed E-keys: keysE[d][n] = exp(2*K)
  #pragma unroll
  for (int m=0;m<16;m++){
    int idx = m*256+t; int nl = idx & 31, d = idx >> 5;
    float kk = os[nl*129 + d] / nrm[nl];
    keysE[(size_t)d*TTOT + n0 + nl] = __builtin_amdgcn_exp2f(kk * LOG2E2);
  }
  for (int c=0;c<3;c++){
    __syncthreads();
    load_w128(Ws, Wih + c*16384, t);
    __syncthreads();
    float acc[4][4];
    mm_tile(xs, Ws, acc, jg, ng);
    #pragma unroll
    for (int r=0;r<4;r++){
      float bb = bih[c*128 + jg*4+r];
      #pragma unroll
      for (int cc=0;cc<4;cc++)
        giall[(size_t)(n0 + ng*4+cc)*384 + c*128 + jg*4 + r] = acc[r][cc] + bb;
    }
  }
}

// ---------------- Kernel 2: sequential decode ----------------
// 32 blocks x 512 threads; 255 steps; 4 barriers/step.
// Matvec: 8-lane groups x 16-float k-chunks, pair of output rows per group ->
// 4 ds_read_b128/lane/phase. h/qh in PAD16 layout (chunk stride 20): the 8
// chunk bases hit 8 DISTINCT bank quads (R15's H2A bases aliased pairwise on
// 4 quads -> 2-way conflict on every read, +3.1M conflicts, +50us). fp
// computation order identical to R15 (passed, absmax 0.03125).

__global__ __launch_bounds__(512, 2) void decode_kernel(
    const float* __restrict__ emb,
    const float* __restrict__ keysE, const float* __restrict__ giall,
    const float* __restrict__ Whh, const float* __restrict__ bhh,
    const float* __restrict__ Wq1, const float* __restrict__ bq1,
    const float* __restrict__ Wq2, const float* __restrict__ bq2,
    const float* __restrict__ v,   const float* __restrict__ Wh,
    const float* __restrict__ bh,  const int* __restrict__ start_nodes,
    float* __restrict__ tours_o, float* __restrict__ lp_o)
{
  __shared__ __align__(16) float keys_s[128*KSTRIDE];  // 132 KB, transposed E-keys
  __shared__ __align__(16) float h_s[2][160];          // PAD16 layout
  __shared__ __align__(16) float qh_s[160];            // PAD16 layout
  __shared__ __align__(16) float q_s[160];             // PAD16 (raw q), also gctx scratch
  __shared__ __align__(16) float v_sp[160];            // PAD16 layout, -2*v
  __shared__ __align__(16) float spartS[8*SSTR];       // score partials (+init scratch)
  __shared__ int col2node_s[256], node2col_s[256];
  __shared__ float red2[8];

  const int t = threadIdx.x;
  const int b = blockIdx.x;
  const int w  = t >> 6, L  = t & 63;
  const int G  = t >> 3, u = t & 7;     // 64 groups x 8 lanes (matvec)
  const int sel = (t >> 2) & 1;         // which row of the group's pair
  const int myrow = 2*G + sel;          // output row for active lanes
  const int act = ((t & 3) == 0);       // active-lane predicate (u==0 or u==4)
  const int oct = L & 7, dgrp = L >> 3; // score: col-octet, dim-group

  // register weights (160 persistent floats):
  // whh6[r][i]: r=0..2 rows {2G,128+2G,256+2G}; r=3..5 rows {2G+1,...}; chunk u*16
  float4 whh6[6][4], wq14[8], wq24[8];
  {
    const float4* p0 = (const float4*)(Whh + (size_t)(2*G      )*128 + u*16);
    const float4* p1 = (const float4*)(Whh + (size_t)(128+2*G  )*128 + u*16);
    const float4* p2 = (const float4*)(Whh + (size_t)(256+2*G  )*128 + u*16);
    const float4* p3 = (const float4*)(Whh + (size_t)(2*G+1    )*128 + u*16);
    const float4* p4 = (const float4*)(Whh + (size_t)(128+2*G+1)*128 + u*16);
    const float4* p5 = (const float4*)(Whh + (size_t)(256+2*G+1)*128 + u*16);
    const float4* q1a = (const float4*)(Wq1 + (size_t)(2*G  )*128 + u*16);
    const float4* q1b = (const float4*)(Wq1 + (size_t)(2*G+1)*128 + u*16);
    const float4* q2a = (const float4*)(Wq2 + (size_t)(2*G  )*128 + u*16);
    const float4* q2b = (const float4*)(Wq2 + (size_t)(2*G+1)*128 + u*16);
    #pragma unroll
    for (int i=0;i<4;i++){
      whh6[0][i]=p0[i]; whh6[1][i]=p1[i]; whh6[2][i]=p2[i];
      whh6[3][i]=p3[i]; whh6[4][i]=p4[i]; whh6[5][i]=p5[i];
      wq14[i]=q1a[i]; wq14[4+i]=q1b[i];
      wq24[i]=q2a[i]; wq24[4+i]=q2b[i];
    }
  }
  const float br = bhh[myrow], bz = bhh[128+myrow], bn = bhh[256+myrow];
  const float b1g = bq1[myrow], b2g = bq2[myrow];
  // h-chunk base in PAD16 layout: chunk u -> floats [u*20, u*20+16), 16B-aligned
  const int hoff = u*20;

  if (t<128) v_sp[PAD16(t)] = -2.f * v[t];
  if (t<256){ col2node_s[t] = t; node2col_s[t] = t; }
  { // stage transposed E-keys: coalesced per d-row
    #pragma unroll
    for (int m=0;m<16;m++){
      int idx = m*512 + t; int d = idx>>6, q = idx&63;
      *(float4*)(keys_s + d*KSTRIDE + q*4) =
        *(const float4*)(keysE + (size_t)d*TTOT + b*256 + q*4);
    }
  }
  { // graph-context partial sums (4 parts x 64 nodes)
    int d = t & 127, part = t >> 7;
    float a = 0.f;
    const float* base = emb + (size_t)(b*256 + part*64)*128 + d;
    for (int i=0;i<64;i++) a += base[(size_t)i*128];
    spartS[part*128+d] = a;
  }
  int cur = start_nodes[b];
  __syncthreads();
  if (t<128){
    float a = 0.f;
    #pragma unroll
    for (int p=0;p<4;p++) a += spartS[p*128+t];
    q_s[t] = a * (1.f/256.f);          // gctx temp (plain idx, init only)
  }
  __syncthreads();
  if (t<128){ // hidden0 = gctx@Wh.T + bh  (write PAD16)
    float a = bh[t];
    const float* wr = Wh + (size_t)t*128;
    for (int k=0;k<128;k++) a += wr[k]*q_s[k];
    h_s[0][PAD16(t)] = a;
  }
  { // sv = sum(v)
    float xv = (t<128) ? v[t] : 0.f;
    float tot = dpp_wave_sum(xv);
    if (L==0) red2[w] = tot;
  }
  __syncthreads();
  float sv = 0.f;
  #pragma unroll
  for (int i=0;i<8;i++) sv += red2[i];

  // gi prefetch for step 0
  float gir=0.f, giz=0.f, gin=0.f;
  if (act){
    const float* gp = giall + (size_t)cur*384 + myrow;
    gir = gp[0]; giz = gp[128]; gin = gp[256];
  }

  for (int step=0; step<255; step++){
    const int par = step & 1;
    const int V   = 255 - step;          // valid count after removing cur
    const int curl = cur - b*256;

    // ---- swap-remove cur's keys column (waves 2-3; reads PRE-update map) ----
    if (t >= 128 && t < 256){
      int r = t - 128;
      int px = node2col_s[curl];
      keys_s[r*KSTRIDE + px] = keys_s[r*KSTRIDE + V];
    }
    if (t == 384) tours_o[b*256+step] = (float)cur;   // wave 6

    // ---- phase A: gh dots (pair of rows per group) + fused GRU ----
    {
      const float4* hc4 = (const float4*)(h_s[par] + hoff);
      float4 hv0 = hc4[0], hv1 = hc4[1], hv2 = hc4[2], hv3 = hc4[3];
      float a0 = dot4(whh6[0][0],hv0)+dot4(whh6[0][1],hv1)+dot4(whh6[0][2],hv2)+dot4(whh6[0][3],hv3);
      float a1 = dot4(whh6[1][0],hv0)+dot4(whh6[1][1],hv1)+dot4(whh6[1][2],hv2)+dot4(whh6[1][3],hv3);
      float a2 = dot4(whh6[2][0],hv0)+dot4(whh6[2][1],hv1)+dot4(whh6[2][2],hv2)+dot4(whh6[2][3],hv3);
      float a3 = dot4(whh6[3][0],hv0)+dot4(whh6[3][1],hv1)+dot4(whh6[3][2],hv2)+dot4(whh6[3][3],hv3);
      float a4 = dot4(whh6[4][0],hv0)+dot4(whh6[4][1],hv1)+dot4(whh6[4][2],hv2)+dot4(whh6[4][3],hv3);
      float a5 = dot4(whh6[5][0],hv0)+dot4(whh6[5][1],hv1)+dot4(whh6[5][2],hv2)+dot4(whh6[5][3],hv3);
      a0 = red8_lo(a0); a1 = red8_lo(a1); a2 = red8_lo(a2);   // valid at u==0
      a3 = red8_hi(a3); a4 = red8_hi(a4); a5 = red8_hi(a5);   // valid at u==4
      if (act){
        float gr = sel ? a3 : a0;
        float gz = sel ? a4 : a1;
        float gn = sel ? a5 : a2;
        float r = sigfast(gir + gr + br);
        float z = sigfast(giz + gz + bz);
        float n = tanhfast(gin + r*(gn + bn));
        h_s[par^1][PAD16(myrow)] = (1.f-z)*n + z*h_s[par][PAD16(myrow)];
      }
    }
    __syncthreads();                                   // B1

    // ---- deferred index-map update (wave 7; race-free: all prev-step
    //      combine reads of col2node_s completed before B1) ----
    if (t == 448){
      int px = node2col_s[curl];
      int ln = col2node_s[V];
      col2node_s[px] = ln;
      node2col_s[ln] = px;
    }

    { // qh = relu(h@Wq1.T + bq1), pair of rows per group
      const float4* hc4 = (const float4*)(h_s[par^1] + hoff);
      float4 hv0 = hc4[0], hv1 = hc4[1], hv2 = hc4[2], hv3 = hc4[3];
      float a0 = dot4(wq14[0],hv0)+dot4(wq14[1],hv1)+dot4(wq14[2],hv2)+dot4(wq14[3],hv3);
      float a1 = dot4(wq14[4],hv0)+dot4(wq14[5],hv1)+dot4(wq14[6],hv2)+dot4(wq14[7],hv3);
      a0 = red8_lo(a0); a1 = red8_hi(a1);
      if (act) qh_s[PAD16(myrow)] = fmaxf((sel ? a1 : a0) + b1g, 0.f);
    }
    __syncthreads();                                   // B2

    { // q_raw = qh@Wq2.T + bq2 (PAD16 store) ; per-wave ssq via DPP
      const float4* qc4 = (const float4*)(qh_s + hoff);
      float4 qv0 = qc4[0], qv1 = qc4[1], qv2 = qc4[2], qv3 = qc4[3];
      float a0 = dot4(wq24[0],qv0)+dot4(wq24[1],qv1)+dot4(wq24[2],qv2)+dot4(wq24[3],qv3);
      float a1 = dot4(wq24[4],qv0)+dot4(wq24[5],qv1)+dot4(wq24[6],qv2)+dot4(wq24[7],qv3);
      a0 = red8_lo(a0); a1 = red8_hi(a1);
      float qval = (sel ? a1 : a0) + b2g;
      if (act) q_s[PAD16(myrow)] = qval;
      float ssp = act ? qval*qval : 0.f;
      float tot = dpp_wave_sum(ssp);
      if (L==0) red2[w] = tot;
    }
    __syncthreads();                                   // B3

    // ---- score: wave w -> cols 32w..32w+31 (wave skip when 32w >= V;
    //      per-lane skip when its 4-col strip starts >= V) ----
    if (32*w < V){
      float ss = 0.f;
      #pragma unroll
      for (int i=0;i<8;i++) ss += red2[i];
      float rn = 1.f / fmaxf(sqrtf(ss), 1e-12f);
      if (32*w + oct*4 < V){
        const float* kbase = keys_s + dgrp*16*KSTRIDE + 32*w + oct*4;
        const float* qb    = q_s  + dgrp*20;
        const float* vbase = v_sp + dgrp*20;
        float4 acc = {0.f,0.f,0.f,0.f};
        #pragma unroll
        for (int jj=0;jj<16;jj++){
          float eqj = __builtin_amdgcn_exp2f(qb[jj] * rn * LOG2E2);
          float vj  = vbase[jj];
          float4 K = *(const float4*)(kbase + jj*KSTRIDE);
          float r0 = __builtin_amdgcn_rcpf(fmaf(K.x, eqj, 1.f));
          float r1 = __builtin_amdgcn_rcpf(fmaf(K.y, eqj, 1.f));
          float r2 = __builtin_amdgcn_rcpf(fmaf(K.z, eqj, 1.f));
          float r3 = __builtin_amdgcn_rcpf(fmaf(K.w, eqj, 1.f));
          acc.x = fmaf(vj, r0, acc.x);
          acc.y = fmaf(vj, r1, acc.y);
          acc.z = fmaf(vj, r2, acc.z);
          acc.w = fmaf(vj, r3, acc.w);
        }
        *(float4*)(spartS + dgrp*SSTR + 32*w + oct*4) = acc;
      }
    }
    __syncthreads();                                   // Bs1

    // ---- redundant combine: EVERY wave reduces cols < V; every lane
    //      learns argmax + softmax sum -> no extra barrier ----
    {
      float sx=0.f, sy=0.f, sz=0.f, sw=0.f;
      int c0 = 4*L;
      if (c0 < V){
        const float* sp = spartS + c0;
        #pragma unroll
        for (int i=0;i<8;i++){
          float4 p = *(const float4*)(sp + i*SSTR);
          sx += p.x; sy += p.y; sz += p.z; sw += p.w;
        }
      }
      float vx = (c0+0 < V) ? sv+sx : -INFINITY;
      float vy = (c0+1 < V) ? sv+sy : -INFINITY;
      float vz = (c0+2 < V) ? sv+sz : -INFINITY;
      float vw = (c0+3 < V) ? sv+sw : -INFINITY;
      float bm = vx; int bc = c0;                 // first-max tie-break
      if (vy > bm){ bm=vy; bc=c0+1; }
      if (vz > bm){ bm=vz; bc=c0+2; }
      if (vw > bm){ bm=vw; bc=c0+3; }
      float m = dpp_wave_max(bm);
      unsigned long long mk = __ballot(bm == m);
      int flane = __ffsll(mk) - 1;                // lowest lane = lowest col
      int besti = __builtin_amdgcn_readlane(bc, flane);
      float es = __builtin_amdgcn_exp2f((vx-m)*LOG2E) + __builtin_amdgcn_exp2f((vy-m)*LOG2E)
               + __builtin_amdgcn_exp2f((vz-m)*LOG2E) + __builtin_amdgcn_exp2f((vw-m)*LOG2E);
      float S = dpp_wave_sum(es);
      cur = b*256 + col2node_s[besti];            // read pre-next-update map
      if (act){   // prefetch next gi (consumed in next phase A)
        const float* gp = giall + (size_t)cur*384 + myrow;
        gir = gp[0]; giz = gp[128]; gin = gp[256];
      }
      if (t==320) lp_o[b*255+step] = logf(1.f/S + 1e-10f);  // wave 5
    }
    // no barrier: next step's keys-swap/phase-A touch no combine-read state
  }
  if (t==0) tours_o[b*256+255] = (float)cur;
}

extern "C" void kernel_launch(void* const* d_in, const int* in_sizes, int n_in,
                              void* d_out, int out_size, void* d_ws, size_t ws_size,
                              hipStream_t stream) {
  const float* emb  = (const float*)d_in[0];
  const int*   startn = (const int*)d_in[1];
  const float* Wq1 = (const float*)d_in[3];  const float* bq1 = (const float*)d_in[4];
  const float* Wq2 = (const float*)d_in[5];  const float* bq2 = (const float*)d_in[6];
  const float* Wk1 = (const float*)d_in[7];  const float* bk1 = (const float*)d_in[8];
  const float* Wk2 = (const float*)d_in[9];  const float* bk2 = (const float*)d_in[10];
  const float* Wih = (const float*)d_in[11]; const float* Whh = (const float*)d_in[12];
  const float* bih = (const float*)d_in[13]; const float* bhh = (const float*)d_in[14];
  const float* v   = (const float*)d_in[15]; const float* Wh  = (const float*)d_in[16];
  const float* bh  = (const float*)d_in[17];

  float* keysE = (float*)d_ws;               // exp(2*keys) TRANSPOSED [128][8192]
  float* giall = keysE + (size_t)TTOT*DD;    // [8192*384]

  float* outp = (float*)d_out;   // tours [32*256] then log_probs [32*255]

  precompute_kernel<<<256, 256, 0, stream>>>(emb, Wk1, bk1, Wk2, bk2, Wih, bih, keysE, giall);
  decode_kernel<<<NGR, 512, 0, stream>>>(emb, keysE, giall, Whh, bhh, Wq1, bq1, Wq2, bq2,
                                         v, Wh, bh, startn, outp, outp + TTOT);
}